// Round 3
// baseline (553.206 us; speedup 1.0000x reference)
//
#include <hip/hip_runtime.h>

#define Bsz 512
#define Lsz 512
#define Tsz 128
#define TAG_START 126
#define TAG_STOP 127
#define SPB 16            // sequences per block (= MFMA N)
#define UPITCH 136        // u_lds row pitch in bf16 elems (128 + 8 pad)
#define EPITCH 132        // ee ring row pitch in f32 (128 + 4 pad)
#define NSLOT 12          // ee ring depth (2 blocks of SBLK)
#define SBLK 6            // steps per sync block

typedef __attribute__((ext_vector_type(8))) short short8;   // 8 bf16 = MFMA A/B frag
typedef __attribute__((ext_vector_type(4))) float f32x4;    // MFMA C/D frag

__device__ __forceinline__ unsigned pack_bf16(float lo, float hi) {
  unsigned a = (__float_as_uint(lo) + 0x8000u) >> 16;
  unsigned b = (__float_as_uint(hi) + 0x8000u) & 0xFFFF0000u;
  return b | a;
}
__device__ __forceinline__ float bf16lo(unsigned d) { return __uint_as_float(d << 16); }
__device__ __forceinline__ float bf16hi(unsigned d) { return __uint_as_float(d & 0xFFFF0000u); }

// One block = 16 sequences, 256 threads = 4 waves.
// Wave 0 ("chain") owns ALL 8 M-tiles: per step 32 mfma_f32_16x16x32_bf16 sharing
// the same 4 B-frags. u(t)->u(t+1) is a SAME-WAVE LDS write->read (lgkmcnt only,
// NO barrier in the recurrence). Waves 1-3 ("helpers") precompute exp(feats) f32
// into a 12-slot LDS ring, 6 steps ahead, synced by one __syncthreads per 6 steps.
// Numerics replicate the verified 8-wave kernel op-for-op (same pack rounding,
// same (acc*rce)*ee association, same eta-from-packed-word, same terminal tree,
// same gold lane pattern) -> absmax 0.0 expected.
__global__ __launch_bounds__(256, 1) void crf_fwd_kernel(
    const float* __restrict__ feats, const float* __restrict__ trans,
    const int* __restrict__ tags, const int* __restrict__ lens,
    float* __restrict__ diff_out)
{
  __shared__ __align__(16) unsigned short u_lds[2][SPB][UPITCH];   // ~8.7 KB
  __shared__ __align__(16) float ee_ring[NSLOT][SPB][EPITCH];      // ~101 KB
  __shared__ float gold_sh[SPB];
  __shared__ int msh;

  const int g    = blockIdx.x;
  const int tid  = threadIdx.x;
  const int w    = tid >> 6;      // wave 0 = chain, 1..3 = helpers
  const int lane = tid & 63;
  const int q    = lane >> 4;     // quad
  const int s    = lane & 15;     // column: seq-in-block / MFMA n
  const int seq  = g * SPB + s;
  const int lim  = lens[seq] - 1;

  if (tid == 0) msh = 1;
  __syncthreads();
  if (tid < SPB) atomicMax(&msh, lens[g * SPB + tid]);
  for (int i = tid; i < 2 * SPB * UPITCH; i += 256)
    ((unsigned short*)u_lds)[i] = 0;
  __syncthreads();
  const int maxlen = msh;
  if (tid < SPB) u_lds[0][tid][TAG_START] = 0x3F80;   // bf16 1.0

  const int nblk = (maxlen + SBLK - 1) / SBLK;

  // helper: compute exp(feats[.,t,.]) f32 for all 16 seqs x 128 rows into ring
  auto produce = [&](int t, int slot) {
    int tc = t < Lsz ? t : (Lsz - 1);
    int seq16 = lane >> 2, rb = (lane & 3) * 32;
    const float* src = feats + ((size_t)(g * SPB + seq16) * Lsz + tc) * Tsz + rb;
    float* dst = &ee_ring[slot][seq16][rb];
    #pragma unroll
    for (int k2 = 0; k2 < 8; ++k2) {
      float4 v = *(const float4*)(src + 4 * k2);
      float4 e;
      e.x = __expf(v.x); e.y = __expf(v.y); e.z = __expf(v.z); e.w = __expf(v.w);
      *(float4*)(dst + 4 * k2) = e;
    }
  };

  short8 af[8][4];            // exp(trans) A-frags, all 8 tiles (chain only)
  float ucap[8][4];
  float m_run = 0.f, mcap = 0.f;

  if (w == 0) {
    // A-frags: af[i][c] elem j = exp(trans[i*16+s][32c+8q+j]) bf16 (same as before)
    #pragma unroll
    for (int i = 0; i < 8; ++i) {
      const float* tr = trans + (size_t)(i * 16 + s) * Tsz + q * 8;
      #pragma unroll
      for (int c = 0; c < 4; ++c) {
        float4 x = *(const float4*)(tr + c * 32);
        float4 y = *(const float4*)(tr + c * 32 + 4);
        union { unsigned u[4]; short8 v; } cv;
        cv.u[0] = pack_bf16(__expf(x.x), __expf(x.y));
        cv.u[1] = pack_bf16(__expf(x.z), __expf(x.w));
        cv.u[2] = pack_bf16(__expf(y.x), __expf(y.y));
        cv.u[3] = pack_bf16(__expf(y.z), __expf(y.w));
        af[i][c] = cv.v;
      }
      ucap[i][0] = ucap[i][1] = ucap[i][2] = ucap[i][3] = 1.0f;
    }
  } else {
    for (int t = w - 1; t < SBLK; t += 3) produce(t, t);   // block 0 -> slots 0..5
  }
  __syncthreads();

  for (int blk = 0; blk < nblk; ++blk) {
    const int sb = (blk & 1) ? SBLK : 0;          // this block's slot base
    if (w == 0) {
      #pragma unroll
      for (int k = 0; k < SBLK; ++k) {
        const int t = blk * SBLK + k;
        const int rbuf = k & 1;                   // t even -> buf 0 (blk*6 even)
        // ee reads (independent of u chain; issue early)
        float4 ev[8];
        const float* er = &ee_ring[sb + k][s][4 * q];
        #pragma unroll
        for (int i = 0; i < 8; ++i) ev[i] = *(const float4*)(er + 16 * i);
        // u reads: full 128-row u for column s, shared by all 8 tiles
        const unsigned short* ub = &u_lds[rbuf][s][0];
        short8 bq0 = *(const short8*)(ub + 0 * 32 + q * 8);
        short8 bq1 = *(const short8*)(ub + 1 * 32 + q * 8);
        short8 bq2 = *(const short8*)(ub + 2 * 32 + q * 8);
        short8 bq3 = *(const short8*)(ub + 3 * 32 + q * 8);
        unsigned ud = *(const unsigned*)ub;
        f32x4 acc[8];
        #pragma unroll
        for (int i = 0; i < 8; ++i) {
          f32x4 a = {0.f, 0.f, 0.f, 0.f};
          a = __builtin_amdgcn_mfma_f32_16x16x32_bf16(af[i][0], bq0, a, 0, 0, 0);
          a = __builtin_amdgcn_mfma_f32_16x16x32_bf16(af[i][1], bq1, a, 0, 0, 0);
          a = __builtin_amdgcn_mfma_f32_16x16x32_bf16(af[i][2], bq2, a, 0, 0, 0);
          a = __builtin_amdgcn_mfma_f32_16x16x32_bf16(af[i][3], bq3, a, 0, 0, 0);
          acc[i] = a;
        }
        float eta = bf16lo(ud) + bf16hi(ud);
        if (t == 0) eta = 1.0f;
        float rce = __builtin_amdgcn_rcpf(eta);
        float uv[8][4];
        #pragma unroll
        for (int i = 0; i < 8; ++i) {
          uv[i][0] = acc[i][0] * rce * ev[i].x;
          uv[i][1] = acc[i][1] * rce * ev[i].y;
          uv[i][2] = acc[i][2] * rce * ev[i].z;
          uv[i][3] = acc[i][3] * rce * ev[i].w;
        }
        m_run += __logf(eta);
        if (t == lim) {                            // capture (rare, exec-masked)
          #pragma unroll
          for (int i = 0; i < 8; ++i) {
            ucap[i][0] = uv[i][0]; ucap[i][1] = uv[i][1];
            ucap[i][2] = uv[i][2]; ucap[i][3] = uv[i][3];
          }
          mcap = m_run;
        }
        unsigned short* dstp = &u_lds[rbuf ^ 1][s][0];
        #pragma unroll
        for (int i = 0; i < 8; ++i) {
          uint2 pk;
          pk.x = pack_bf16(uv[i][0], uv[i][1]);
          pk.y = pack_bf16(uv[i][2], uv[i][3]);
          *(uint2*)(dstp + 16 * i + 4 * q) = pk;
        }
      }
    } else {
      // produce block blk+1 into the other ring half (disjoint from chain's reads)
      const int b2 = (blk + 1) * SBLK;
      const int sb2 = ((blk + 1) & 1) ? SBLK : 0;
      for (int j = w - 1; j < SBLK; j += 3) produce(b2 + j, sb2 + j);
    }
    __syncthreads();
  }

  // ---- terminal logsumexp (chain wave only; replicates old 4-wave tree) ----
  float fwd_score = 0.f;
  if (w == 0) {
    float fvv[8][4];
    const float* tr2 = trans + TAG_START * Tsz + 4 * q;
    #pragma unroll
    for (int i = 0; i < 8; ++i) {
      float4 tv = *(const float4*)(tr2 + 16 * i);
      fvv[i][0] = __logf(ucap[i][0]) + mcap + tv.x;
      fvv[i][1] = __logf(ucap[i][1]) + mcap + tv.y;
      fvv[i][2] = __logf(ucap[i][2]) + mcap + tv.z;
      fvv[i][3] = __logf(ucap[i][3]) + mcap + tv.w;
    }
    float redm[4], reds[4];
    #pragma unroll
    for (int w2 = 0; w2 < 4; ++w2) {
      float mx = fvv[2 * w2][0];
      mx = fmaxf(mx, fvv[2 * w2][1]);
      mx = fmaxf(mx, fvv[2 * w2][2]);
      mx = fmaxf(mx, fvv[2 * w2][3]);
      mx = fmaxf(mx, fvv[2 * w2 + 1][0]);
      mx = fmaxf(mx, fvv[2 * w2 + 1][1]);
      mx = fmaxf(mx, fvv[2 * w2 + 1][2]);
      mx = fmaxf(mx, fvv[2 * w2 + 1][3]);
      mx = fmaxf(mx, __shfl_xor(mx, 16, 64));
      mx = fmaxf(mx, __shfl_xor(mx, 32, 64));
      redm[w2] = mx;
    }
    float gmx = fmaxf(fmaxf(redm[0], redm[1]), fmaxf(redm[2], redm[3]));
    #pragma unroll
    for (int w2 = 0; w2 < 4; ++w2) {
      float se = 0.f;
      #pragma unroll
      for (int r = 0; r < 4; ++r) se += __expf(fvv[2 * w2][r] - gmx);
      #pragma unroll
      for (int r = 0; r < 4; ++r) se += __expf(fvv[2 * w2 + 1][r] - gmx);
      se += __shfl_xor(se, 16, 64);
      se += __shfl_xor(se, 32, 64);
      reds[w2] = se;
    }
    fwd_score = gmx + __logf((reds[0] + reds[1]) + (reds[2] + reds[3]));
  }

  // ---- gold score: wave w handles seqs 4w+q; 16 lanes per seq (verbatim) ----
  {
    int jj = 4 * w + q;
    int gs2 = g * SPB + jj;
    int lenj = lens[gs2];
    const int* tg = tags + (size_t)gs2 * Lsz;
    const float* fbj = feats + (size_t)gs2 * (Lsz * Tsz);
    float gacc = 0.f;
    for (int pos = s; pos <= lenj; pos += 16) {
      int st = (pos == 0)    ? TAG_START : tg[pos - 1];
      int et = (pos == lenj) ? TAG_STOP  : tg[pos];
      gacc += trans[et * Tsz + st];
    }
    for (int l = s; l < lenj; l += 16)
      gacc += fbj[(size_t)l * Tsz + tg[l]];
    #pragma unroll
    for (int off = 1; off < 16; off <<= 1) gacc += __shfl_xor(gacc, off, 64);
    if (s == 0) gold_sh[jj] = gacc;
  }
  __syncthreads();
  if (w == 0 && q == 0)
    diff_out[g * SPB + s] = fwd_score - gold_sh[s];
}

// loss = mean(diff)
__global__ __launch_bounds__(Bsz) void crf_final_kernel(
    const float* __restrict__ diff, float* __restrict__ out)
{
  int tid = threadIdx.x;
  float v = diff[tid];
  __shared__ float wred[8];
  float sum = v;
  #pragma unroll
  for (int off = 32; off > 0; off >>= 1) sum += __shfl_down(sum, off, 64);
  int wave = tid >> 6, lane = tid & 63;
  if (lane == 0) wred[wave] = sum;
  __syncthreads();
  if (tid == 0) {
    float t = 0.f;
    #pragma unroll
    for (int i = 0; i < 8; ++i) t += wred[i];
    out[0] = t * (1.0f / Bsz);
  }
}

extern "C" void kernel_launch(void* const* d_in, const int* in_sizes, int n_in,
                              void* d_out, int out_size, void* d_ws, size_t ws_size,
                              hipStream_t stream) {
  const float* feats = (const float*)d_in[0];
  const float* trans = (const float*)d_in[1];
  const int*   tags  = (const int*)d_in[2];
  const int*   lens  = (const int*)d_in[3];
  float* out  = (float*)d_out;
  float* diff = (float*)d_ws;

  crf_fwd_kernel<<<Bsz / SPB, 256, 0, stream>>>(feats, trans, tags, lens, diff);
  crf_final_kernel<<<1, Bsz, 0, stream>>>(diff, out);
}